// Round 3
// baseline (687.423 us; speedup 1.0000x reference)
//
#include <hip/hip_runtime.h>

#define PYR 40000
#define N_PV 2100
#define N_OLM 1800
#define N_BIST 1200
#define N_SEPT 100

// ws layout (floats)
#define WS_PV_RAW   0        // [2100]
#define WS_OLM_RAW  2100     // [1800]
#define WS_BIST_RAW 3900     // [1200]
#define WS_PV_LAT   5100     // [2100]
#define WS_OLM_IPV  7200     // [2100]
#define WS_GAP      9300     // [2100]
#define WS_OLM_GINH 11400    // [1800]
#define WS_CNT      13200    // [1] int completion counter

// out layout (floats)
#define O_PERI 0
#define O_GABA 40000
#define O_DEND 80000
#define O_OLMD 120000
#define O_PVS  160000
#define O_OLMS 162100
#define O_BIS  163900

typedef float f4 __attribute__((ext_vector_type(4)));
typedef int   i4 __attribute__((ext_vector_type(4)));

__device__ __forceinline__ f4 ntload(const f4* p) { return __builtin_nontemporal_load(p); }

__device__ __forceinline__ float wave_reduce(float acc) {
    #pragma unroll
    for (int o = 32; o > 0; o >>= 1) acc += __shfl_down(acc, o, 64);
    return acc;
}

// wave-per-row dot with compile-time length (in float4 units)
template<int LEN4>
__device__ __forceinline__ float dot_row(const f4* __restrict__ W4,
                                         const f4* __restrict__ V4, int lane) {
    float acc = 0.0f;
    constexpr int FULL = LEN4 / 64;
    constexpr int TAIL = LEN4 % 64;
    #pragma unroll
    for (int it = 0; it < FULL; ++it) {
        int j = lane + it * 64;
        f4 w = ntload(W4 + j), x = V4[j];
        acc += w.x * x.x + w.y * x.y + w.z * x.z + w.w * x.w;
    }
    if (TAIL && lane < TAIL) {
        int j = FULL * 64 + lane;
        f4 w = ntload(W4 + j), x = V4[j];
        acc += w.x * x.x + w.y * x.y + w.z * x.z + w.w * x.w;
    }
    return acc;
}

#define P1_BLOCKS (N_PV + N_OLM + N_BIST)           // 5100
#define SMALL_ROWS (3 * N_PV + N_OLM)               // 8100
#define SMALL_BLOCKS ((SMALL_ROWS + 3) / 4)         // 2025
#define TOTAL_BLOCKS (P1_BLOCKS + SMALL_BLOCKS)     // 7125

// ---- Kernel 1: phase-1 GEMVs + small GEMVs + last-block LIF epilogue
__global__ __launch_bounds__(256) void k_big(
    const float* __restrict__ Wpv, const float* __restrict__ Wolm,
    const float* __restrict__ Wbi, const int* __restrict__ pyr,
    const float* __restrict__ Wpvpv, const float* __restrict__ Wolmpv,
    const float* __restrict__ Wgap,  const float* __restrict__ Wsept,
    const float* __restrict__ prev_pv, const float* __restrict__ prev_olm,
    const float* __restrict__ prev_vm, const float* __restrict__ sept_g,
    const float* __restrict__ ext,
    const float* __restrict__ pv_v,  const float* __restrict__ olm_v,  const float* __restrict__ bist_v,
    const float* __restrict__ pv_ad, const float* __restrict__ olm_ad, const float* __restrict__ bist_ad,
    float* __restrict__ ws, float* __restrict__ out, int* __restrict__ counter)
{
    __shared__ float sm[4];
    __shared__ int   is_last;
    __shared__ float s1[256], s2[256];

    int b = blockIdx.x;
    int lane = threadIdx.x & 63;

    if (b < P1_BLOCKS) {
        const float* W; float* dst;
        if (b < N_PV)               { W = Wpv  + (size_t)b * PYR;                   dst = ws + WS_PV_RAW  + b; }
        else if (b < N_PV + N_OLM)  { int r = b - N_PV;         W = Wolm + (size_t)r * PYR; dst = ws + WS_OLM_RAW  + r; }
        else                        { int r = b - N_PV - N_OLM; W = Wbi  + (size_t)r * PYR; dst = ws + WS_BIST_RAW + r; }

        const f4* W4 = (const f4*)W;
        const i4* S4 = (const i4*)pyr;
        float acc = 0.0f;
        // PYR/4 = 10000 f4 elems; 39 full strides of 256, tail of 16
        #pragma unroll 4
        for (int it = 0; it < 39; ++it) {
            int j = threadIdx.x + it * 256;
            f4 w = ntload(W4 + j);
            i4 s = S4[j];
            acc += w.x * (float)s.x + w.y * (float)s.y + w.z * (float)s.z + w.w * (float)s.w;
        }
        if (threadIdx.x < 16) {
            int j = 9984 + threadIdx.x;
            f4 w = ntload(W4 + j);
            i4 s = S4[j];
            acc += w.x * (float)s.x + w.y * (float)s.y + w.z * (float)s.z + w.w * (float)s.w;
        }
        acc = wave_reduce(acc);
        int wv = threadIdx.x >> 6;
        if (lane == 0) sm[wv] = acc;
        __syncthreads();
        if (threadIdx.x == 0) *dst = sm[0] + sm[1] + sm[2] + sm[3];
    } else {
        int r = (b - P1_BLOCKS) * 4 + (threadIdx.x >> 6);
        float res = 0.0f; float* dst = nullptr;
        if (r < N_PV) {
            dst = ws + WS_PV_LAT + r;
            res = dot_row<525>((const f4*)(Wpvpv + (size_t)r * N_PV), (const f4*)prev_pv, lane);
        } else if (r < 2 * N_PV) {
            int i = r - N_PV; dst = ws + WS_OLM_IPV + i;
            res = dot_row<450>((const f4*)(Wolmpv + (size_t)i * N_OLM), (const f4*)prev_olm, lane);
        } else if (r < 3 * N_PV) {
            int i = r - 2 * N_PV; dst = ws + WS_GAP + i;
            res = dot_row<525>((const f4*)(Wgap + (size_t)i * N_PV), (const f4*)prev_vm, lane);
        } else if (r < SMALL_ROWS) {
            int i = r - 3 * N_PV; dst = ws + WS_OLM_GINH + i;
            res = dot_row<25>((const f4*)(Wsept + (size_t)i * N_SEPT), (const f4*)sept_g, lane);
        }
        if (dst) {
            res = wave_reduce(res);
            if (lane == 0) *dst = res;
        }
    }

    // ---- last-block-done LIF epilogue
    __syncthreads();
    if (threadIdx.x == 0) {
        __threadfence();                          // publish this block's ws writes
        int old = atomicAdd(counter, 1);
        is_last = (old == TOTAL_BLOCKS - 1) ? 1 : 0;
    }
    __syncthreads();
    if (!is_last) return;
    __threadfence();                              // acquire: see all blocks' ws writes

    float a = 0.0f, bs = 0.0f;
    for (int i = threadIdx.x; i < N_PV; i += 256) { a += ext[i]; bs += ws[WS_PV_RAW + i]; }
    s1[threadIdx.x] = a; s2[threadIdx.x] = bs;
    __syncthreads();
    for (int o = 128; o > 0; o >>= 1) {
        if (threadIdx.x < o) { s1[threadIdx.x] += s1[threadIdx.x + o]; s2[threadIdx.x] += s2[threadIdx.x + o]; }
        __syncthreads();
    }
    float ext_mean = s1[0] / (float)N_PV;
    float drive    = s2[0] / (float)N_PV;
    float gain = (drive > 0.01f) ? fminf(1.0f, drive / 0.1f) : 0.0f;

    for (int t = threadIdx.x; t < N_PV + N_OLM + N_BIST; t += 256) {
        if (t < N_PV) {
            float g = ws[WS_PV_RAW + t] + ext_mean * 0.3f
                    - ws[WS_PV_LAT + t] * 0.5f - ws[WS_OLM_IPV + t] * 0.3f
                    + ws[WS_GAP + t] * 0.05f * gain;
            g = fmaxf(g, 0.0f);
            float v = pv_v[t], ad = pv_ad[t];
            float vn = v + (1.0f / 7.0f) * (-v + g * (3.0f - v));
            out[O_PVS + t] = (vn >= 2.0f + ad) ? 1.0f : 0.0f;
        } else if (t < N_PV + N_OLM) {
            int i = t - N_PV;
            float g = fmaxf(ws[WS_OLM_RAW + i] + ext_mean * 0.1f, 0.0f);
            float gi = ws[WS_OLM_GINH + i];
            float v = olm_v[i], ad = olm_ad[i];
            float vn = v + (1.0f / 25.0f) * (-v + g * (3.0f - v) + gi * (-0.5f - v));
            out[O_OLMS + i] = (vn >= 1.1f + ad) ? 1.0f : 0.0f;
        } else {
            int i = t - N_PV - N_OLM;
            float g = fmaxf(ws[WS_BIST_RAW + i] + ext_mean * 0.2f, 0.0f);
            float v = bist_v[i], ad = bist_ad[i];
            float vn = v + (1.0f / 12.0f) * (-v + g * (3.0f - v));
            out[O_BIS + i] = (vn >= 0.9f + ad) ? 1.0f : 0.0f;
        }
    }
}

// ---- Kernel 2: phase-2 GEMVs, wave-per-row; olm+bist fused -> dendritic direct
__global__ __launch_bounds__(256) void k_phase2(
    const float* __restrict__ Wpp, const float* __restrict__ Wppb,
    const float* __restrict__ Wop, const float* __restrict__ Wbp,
    float* __restrict__ out)
{
    int r = blockIdx.x * 4 + (threadIdx.x >> 6);  // 0 .. 3*PYR-1
    int lane = threadIdx.x & 63;
    int job = r / PYR;
    int p = r - job * PYR;

    if (job < 2) {
        const float* W = (job == 0 ? Wpp : Wppb) + (size_t)p * N_PV;
        float acc = dot_row<525>((const f4*)W, (const f4*)(out + O_PVS), lane);
        acc = wave_reduce(acc);
        if (lane == 0) out[(job == 0 ? O_PERI : O_GABA) + p] = acc;
    } else {
        float ao = dot_row<450>((const f4*)(Wop + (size_t)p * N_OLM),  (const f4*)(out + O_OLMS), lane);
        float ab = dot_row<300>((const f4*)(Wbp + (size_t)p * N_BIST), (const f4*)(out + O_BIS),  lane);
        ao = wave_reduce(ao);
        ab = wave_reduce(ab);
        if (lane == 0) {
            out[O_OLMD + p] = ao;
            out[O_DEND + p] = ao + ab;
        }
    }
}

extern "C" void kernel_launch(void* const* d_in, const int* in_sizes, int n_in,
                              void* d_out, int out_size, void* d_ws, size_t ws_size,
                              hipStream_t stream)
{
    const int*   pyr     = (const int*)  d_in[0];
    const float* sept_g  = (const float*)d_in[1];
    const float* ext     = (const float*)d_in[2];
    const float* prev_pv = (const float*)d_in[3];
    const float* prev_olm= (const float*)d_in[4];
    const float* prev_vm = (const float*)d_in[5];
    const float* pv_v    = (const float*)d_in[6];
    const float* olm_v   = (const float*)d_in[7];
    const float* bist_v  = (const float*)d_in[8];
    const float* pv_ad   = (const float*)d_in[9];
    const float* olm_ad  = (const float*)d_in[10];
    const float* bist_ad = (const float*)d_in[11];
    const float* Wpyr_pv = (const float*)d_in[12];
    const float* Wpyr_olm= (const float*)d_in[13];
    const float* Wpyr_bi = (const float*)d_in[14];
    const float* Wpp     = (const float*)d_in[15];
    const float* Wppb    = (const float*)d_in[16];
    const float* Wop     = (const float*)d_in[17];
    const float* Wbp     = (const float*)d_in[18];
    const float* Wpvpv   = (const float*)d_in[19];
    const float* Wolmpv  = (const float*)d_in[20];
    const float* Wgap    = (const float*)d_in[21];
    const float* Wsept   = (const float*)d_in[22];

    float* ws  = (float*)d_ws;
    float* out = (float*)d_out;
    int* counter = (int*)(ws + WS_CNT);

    hipMemsetAsync(counter, 0, sizeof(int), stream);

    k_big<<<TOTAL_BLOCKS, 256, 0, stream>>>(
        Wpyr_pv, Wpyr_olm, Wpyr_bi, pyr,
        Wpvpv, Wolmpv, Wgap, Wsept,
        prev_pv, prev_olm, prev_vm, sept_g,
        ext, pv_v, olm_v, bist_v, pv_ad, olm_ad, bist_ad,
        ws, out, counter);
    k_phase2<<<(3 * PYR) / 4, 256, 0, stream>>>(Wpp, Wppb, Wop, Wbp, out);
}

// Round 4
// 322.876 us; speedup vs baseline: 2.1291x; 2.1291x over previous
//
#include <hip/hip_runtime.h>

#define PYR 40000
#define N_PV 2100
#define N_OLM 1800
#define N_BIST 1200
#define N_SEPT 100

// ws layout (floats)
#define WS_PV_RAW   0        // [2100]
#define WS_OLM_RAW  2100     // [1800]
#define WS_BIST_RAW 3900     // [1200]
#define WS_PV_LAT   5100     // [2100]
#define WS_OLM_IPV  7200     // [2100]
#define WS_GAP      9300     // [2100]
#define WS_OLM_GINH 11400    // [1800]

// out layout (floats)
#define O_PERI 0
#define O_GABA 40000
#define O_DEND 80000
#define O_OLMD 120000
#define O_PVS  160000
#define O_OLMS 162100
#define O_BIS  163900

typedef float f4 __attribute__((ext_vector_type(4)));
typedef int   i4 __attribute__((ext_vector_type(4)));

__device__ __forceinline__ f4 ntload(const f4* p) { return __builtin_nontemporal_load(p); }

__device__ __forceinline__ float wave_reduce(float acc) {
    #pragma unroll
    for (int o = 32; o > 0; o >>= 1) acc += __shfl_down(acc, o, 64);
    return acc;
}

// wave-per-row dot with compile-time length (in float4 units)
template<int LEN4>
__device__ __forceinline__ float dot_row(const f4* __restrict__ W4,
                                         const f4* __restrict__ V4, int lane) {
    float acc = 0.0f;
    constexpr int FULL = LEN4 / 64;
    constexpr int TAIL = LEN4 % 64;
    #pragma unroll
    for (int it = 0; it < FULL; ++it) {
        int j = lane + it * 64;
        f4 w = ntload(W4 + j), x = V4[j];
        acc += w.x * x.x + w.y * x.y + w.z * x.z + w.w * x.w;
    }
    if (TAIL && lane < TAIL) {
        int j = FULL * 64 + lane;
        f4 w = ntload(W4 + j), x = V4[j];
        acc += w.x * x.x + w.y * x.y + w.z * x.z + w.w * x.w;
    }
    return acc;
}

#define P1_BLOCKS (N_PV + N_OLM + N_BIST)           // 5100
#define SMALL_ROWS (3 * N_PV + N_OLM)               // 8100
#define SMALL_BLOCKS ((SMALL_ROWS + 3) / 4)         // 2025

// ---- Kernel 1: phase-1 big GEMVs (block-per-row) + small GEMVs (wave-per-row)
__global__ __launch_bounds__(256) void k_big(
    const float* __restrict__ Wpv, const float* __restrict__ Wolm,
    const float* __restrict__ Wbi, const int* __restrict__ pyr,
    const float* __restrict__ Wpvpv, const float* __restrict__ Wolmpv,
    const float* __restrict__ Wgap,  const float* __restrict__ Wsept,
    const float* __restrict__ prev_pv, const float* __restrict__ prev_olm,
    const float* __restrict__ prev_vm, const float* __restrict__ sept_g,
    float* __restrict__ ws)
{
    int b = blockIdx.x;
    int lane = threadIdx.x & 63;

    if (b < P1_BLOCKS) {
        const float* W; float* dst;
        if (b < N_PV)               { W = Wpv  + (size_t)b * PYR;                   dst = ws + WS_PV_RAW  + b; }
        else if (b < N_PV + N_OLM)  { int r = b - N_PV;         W = Wolm + (size_t)r * PYR; dst = ws + WS_OLM_RAW  + r; }
        else                        { int r = b - N_PV - N_OLM; W = Wbi  + (size_t)r * PYR; dst = ws + WS_BIST_RAW + r; }

        const f4* W4 = (const f4*)W;
        const i4* S4 = (const i4*)pyr;
        float acc = 0.0f;
        // PYR/4 = 10000 f4 elems; 39 full strides of 256, tail of 16
        #pragma unroll 4
        for (int it = 0; it < 39; ++it) {
            int j = threadIdx.x + it * 256;
            f4 w = ntload(W4 + j);
            i4 s = S4[j];
            acc += w.x * (float)s.x + w.y * (float)s.y + w.z * (float)s.z + w.w * (float)s.w;
        }
        if (threadIdx.x < 16) {
            int j = 9984 + threadIdx.x;
            f4 w = ntload(W4 + j);
            i4 s = S4[j];
            acc += w.x * (float)s.x + w.y * (float)s.y + w.z * (float)s.z + w.w * (float)s.w;
        }
        acc = wave_reduce(acc);
        __shared__ float sm[4];
        int wv = threadIdx.x >> 6;
        if (lane == 0) sm[wv] = acc;
        __syncthreads();
        if (threadIdx.x == 0) *dst = sm[0] + sm[1] + sm[2] + sm[3];
        return;
    }

    // small GEMVs: wave-per-row
    int r = (b - P1_BLOCKS) * 4 + (threadIdx.x >> 6);
    float res = 0.0f; float* dst = nullptr;
    if (r < N_PV) {
        dst = ws + WS_PV_LAT + r;
        res = dot_row<525>((const f4*)(Wpvpv + (size_t)r * N_PV), (const f4*)prev_pv, lane);
    } else if (r < 2 * N_PV) {
        int i = r - N_PV; dst = ws + WS_OLM_IPV + i;
        res = dot_row<450>((const f4*)(Wolmpv + (size_t)i * N_OLM), (const f4*)prev_olm, lane);
    } else if (r < 3 * N_PV) {
        int i = r - 2 * N_PV; dst = ws + WS_GAP + i;
        res = dot_row<525>((const f4*)(Wgap + (size_t)i * N_PV), (const f4*)prev_vm, lane);
    } else if (r < SMALL_ROWS) {
        int i = r - 3 * N_PV; dst = ws + WS_OLM_GINH + i;
        res = dot_row<25>((const f4*)(Wsept + (size_t)i * N_SEPT), (const f4*)sept_g, lane);
    }
    if (dst) {
        res = wave_reduce(res);
        if (lane == 0) *dst = res;
    }
}

// ---- Kernel 2: per-block redundant scalar reduce (ext_mean, drive->gain) + LIF
__global__ __launch_bounds__(256) void k_lif(
    const float* __restrict__ ws, const float* __restrict__ ext,
    const float* __restrict__ pv_v,  const float* __restrict__ olm_v,  const float* __restrict__ bist_v,
    const float* __restrict__ pv_ad, const float* __restrict__ olm_ad, const float* __restrict__ bist_ad,
    float* __restrict__ out)
{
    __shared__ float s1[256], s2[256];
    float a = 0.0f, bsum = 0.0f;
    for (int i = threadIdx.x; i < N_PV; i += 256) { a += ext[i]; bsum += ws[WS_PV_RAW + i]; }
    s1[threadIdx.x] = a; s2[threadIdx.x] = bsum;
    __syncthreads();
    for (int o = 128; o > 0; o >>= 1) {
        if (threadIdx.x < o) { s1[threadIdx.x] += s1[threadIdx.x + o]; s2[threadIdx.x] += s2[threadIdx.x + o]; }
        __syncthreads();
    }
    float ext_mean = s1[0] / (float)N_PV;
    float drive    = s2[0] / (float)N_PV;
    float gain = (drive > 0.01f) ? fminf(1.0f, drive / 0.1f) : 0.0f;

    int t = blockIdx.x * 256 + threadIdx.x;
    if (t < N_PV) {
        float g = ws[WS_PV_RAW + t] + ext_mean * 0.3f
                - ws[WS_PV_LAT + t] * 0.5f - ws[WS_OLM_IPV + t] * 0.3f
                + ws[WS_GAP + t] * 0.05f * gain;
        g = fmaxf(g, 0.0f);
        float v = pv_v[t], ad = pv_ad[t];
        float vn = v + (1.0f / 7.0f) * (-v + g * (3.0f - v));
        out[O_PVS + t] = (vn >= 2.0f + ad) ? 1.0f : 0.0f;
    } else if (t < N_PV + N_OLM) {
        int i = t - N_PV;
        float g = fmaxf(ws[WS_OLM_RAW + i] + ext_mean * 0.1f, 0.0f);
        float gi = ws[WS_OLM_GINH + i];
        float v = olm_v[i], ad = olm_ad[i];
        float vn = v + (1.0f / 25.0f) * (-v + g * (3.0f - v) + gi * (-0.5f - v));
        out[O_OLMS + i] = (vn >= 1.1f + ad) ? 1.0f : 0.0f;
    } else if (t < N_PV + N_OLM + N_BIST) {
        int i = t - N_PV - N_OLM;
        float g = fmaxf(ws[WS_BIST_RAW + i] + ext_mean * 0.2f, 0.0f);
        float v = bist_v[i], ad = bist_ad[i];
        float vn = v + (1.0f / 12.0f) * (-v + g * (3.0f - v));
        out[O_BIS + i] = (vn >= 0.9f + ad) ? 1.0f : 0.0f;
    }
}

// ---- Kernel 3: phase-2 GEMVs, wave-per-row; olm+bist fused -> dendritic direct
__global__ __launch_bounds__(256) void k_phase2(
    const float* __restrict__ Wpp, const float* __restrict__ Wppb,
    const float* __restrict__ Wop, const float* __restrict__ Wbp,
    float* __restrict__ out)
{
    int r = blockIdx.x * 4 + (threadIdx.x >> 6);  // 0 .. 3*PYR-1
    int lane = threadIdx.x & 63;
    int job = r / PYR;
    int p = r - job * PYR;

    if (job < 2) {
        const float* W = (job == 0 ? Wpp : Wppb) + (size_t)p * N_PV;
        float acc = dot_row<525>((const f4*)W, (const f4*)(out + O_PVS), lane);
        acc = wave_reduce(acc);
        if (lane == 0) out[(job == 0 ? O_PERI : O_GABA) + p] = acc;
    } else {
        float ao = dot_row<450>((const f4*)(Wop + (size_t)p * N_OLM),  (const f4*)(out + O_OLMS), lane);
        float ab = dot_row<300>((const f4*)(Wbp + (size_t)p * N_BIST), (const f4*)(out + O_BIS),  lane);
        ao = wave_reduce(ao);
        ab = wave_reduce(ab);
        if (lane == 0) {
            out[O_OLMD + p] = ao;
            out[O_DEND + p] = ao + ab;
        }
    }
}

extern "C" void kernel_launch(void* const* d_in, const int* in_sizes, int n_in,
                              void* d_out, int out_size, void* d_ws, size_t ws_size,
                              hipStream_t stream)
{
    const int*   pyr     = (const int*)  d_in[0];
    const float* sept_g  = (const float*)d_in[1];
    const float* ext     = (const float*)d_in[2];
    const float* prev_pv = (const float*)d_in[3];
    const float* prev_olm= (const float*)d_in[4];
    const float* prev_vm = (const float*)d_in[5];
    const float* pv_v    = (const float*)d_in[6];
    const float* olm_v   = (const float*)d_in[7];
    const float* bist_v  = (const float*)d_in[8];
    const float* pv_ad   = (const float*)d_in[9];
    const float* olm_ad  = (const float*)d_in[10];
    const float* bist_ad = (const float*)d_in[11];
    const float* Wpyr_pv = (const float*)d_in[12];
    const float* Wpyr_olm= (const float*)d_in[13];
    const float* Wpyr_bi = (const float*)d_in[14];
    const float* Wpp     = (const float*)d_in[15];
    const float* Wppb    = (const float*)d_in[16];
    const float* Wop     = (const float*)d_in[17];
    const float* Wbp     = (const float*)d_in[18];
    const float* Wpvpv   = (const float*)d_in[19];
    const float* Wolmpv  = (const float*)d_in[20];
    const float* Wgap    = (const float*)d_in[21];
    const float* Wsept   = (const float*)d_in[22];

    float* ws  = (float*)d_ws;
    float* out = (float*)d_out;

    k_big<<<P1_BLOCKS + SMALL_BLOCKS, 256, 0, stream>>>(
        Wpyr_pv, Wpyr_olm, Wpyr_bi, pyr,
        Wpvpv, Wolmpv, Wgap, Wsept,
        prev_pv, prev_olm, prev_vm, sept_g, ws);
    k_lif<<<(N_PV + N_OLM + N_BIST + 255) / 256, 256, 0, stream>>>(
        ws, ext, pv_v, olm_v, bist_v, pv_ad, olm_ad, bist_ad, out);
    k_phase2<<<(3 * PYR) / 4, 256, 0, stream>>>(Wpp, Wppb, Wop, Wbp, out);
}